// Round 7
// baseline (3229.876 us; speedup 1.0000x reference)
//
#include <hip/hip_runtime.h>
#include <math.h>

#define NNODES 5000
#define NEDGES 50000
#define NELG   200000
#define DMODEL 512
#define NH     8
#define NLAYERS 2

typedef __bf16 bf16x8 __attribute__((ext_vector_type(8)));
typedef float  f32x4  __attribute__((ext_vector_type(4)));
typedef unsigned short us8v __attribute__((ext_vector_type(8)));

// ---- bf16 helpers (stored as unsigned short) ------------------------------
__device__ __forceinline__ float b2f(unsigned short u) {
    union { unsigned int i; float f; } c;
    c.i = ((unsigned int)u) << 16;
    return c.f;
}
__device__ __forceinline__ unsigned short f2b(float f) {
    union { float f; unsigned int i; } c;
    c.f = f;
    unsigned int i = c.i;
    return (unsigned short)((i + 0x7fffu + ((i >> 16) & 1u)) >> 16);
}

// ---------------------------------------------------------------------------
// MFMA GEMM, BK=64: 8 K-iterations at K=512 — half the barrier/latency
// round-trips of BK=32 (the K-loop is latency-serialized, ~900cyc/iter).
// Grid: x = N-tiles (fast, A-tile reuse in-window), y = M-tiles.
// LDS: slot = chunk ^ (l16&7) XOR swizzle; 16 B granules keep the
// wave-uniform-base + lane*16 constraint of global_load_lds.
// ---------------------------------------------------------------------------
#define BM 128
#define BN 128
#define BK 64

struct GemmDst {
    unsigned short* C0; unsigned short* C1; unsigned short* C2;
    const unsigned short* a0; const unsigned short* a1; const unsigned short* a2;
    const int* x0; const int* x1; const int* x2;
    const float* b0; const float* b1; const float* b2;
};

__global__ __launch_bounds__(256) void mfma_gemm_kernel(
    const unsigned short* __restrict__ A, const unsigned short* __restrict__ Bt,
    GemmDst P, int M, int K, int N, int secN, int relu)
{
    __shared__ __align__(16) unsigned short ldsA[BM * BK];  // 16 KB
    __shared__ __align__(16) unsigned short ldsB[BN * BK];  // 16 KB

    const int rowBase = blockIdx.y * BM;
    const int colBase = blockIdx.x * BN;

    const int tid  = threadIdx.x;
    const int lane = tid & 63;
    const int wave = tid >> 6;
    const int quad = lane >> 4;
    const int l16  = lane & 15;
    const int wm = (wave >> 1) * 64;
    const int wn = (wave & 1) * 64;

    // staging: 1024 groups per operand; group g: row=g>>3, slot=g&7,
    // slot holds global chunk c = slot ^ (row&7). 4 groups/thread/operand.
    const unsigned short* gA[4]; const unsigned short* gB[4];
    unsigned short* lA[4]; unsigned short* lB[4];
    #pragma unroll
    for (int p = 0; p < 4; ++p) {
        const int g = tid + p * 256;
        const int row = g >> 3, slot = g & 7;
        const int ch = slot ^ (row & 7);
        int ra = rowBase + row; if (ra > M - 1) ra = M - 1;
        gA[p] = A + (size_t)ra * K + ch * 8;
        gB[p] = Bt + (size_t)(colBase + row) * K + ch * 8;
        lA[p] = ldsA + g * 8;
        lB[p] = ldsB + g * 8;
    }

    // fragment-read: chunk cidx = s*4+quad lives at slot cidx^(l16&7)
    const int rsw = l16 & 7;

    const f32x4 zv = {0.f, 0.f, 0.f, 0.f};
    f32x4 acc[4][4];
    #pragma unroll
    for (int i = 0; i < 4; ++i)
        #pragma unroll
        for (int j = 0; j < 4; ++j) acc[i][j] = zv;

    for (int k0 = 0; k0 < K; k0 += BK) {
        #pragma unroll
        for (int p = 0; p < 4; ++p)
            __builtin_amdgcn_global_load_lds(
                (const __attribute__((address_space(1))) void*)(gA[p] + k0),
                (__attribute__((address_space(3))) void*)lA[p], 16, 0, 0);
        #pragma unroll
        for (int p = 0; p < 4; ++p)
            __builtin_amdgcn_global_load_lds(
                (const __attribute__((address_space(1))) void*)(gB[p] + k0),
                (__attribute__((address_space(3))) void*)lB[p], 16, 0, 0);
        __syncthreads();

        #pragma unroll
        for (int s = 0; s < 2; ++s) {
            const int ca = ((s * 4 + quad) ^ rsw) * 8;
            bf16x8 af[4], bfr[4];
            #pragma unroll
            for (int i = 0; i < 4; ++i)
                af[i] = *(const bf16x8*)(ldsA + (wm + i * 16 + l16) * BK + ca);
            #pragma unroll
            for (int j = 0; j < 4; ++j)
                bfr[j] = *(const bf16x8*)(ldsB + (wn + j * 16 + l16) * BK + ca);
            #pragma unroll
            for (int i = 0; i < 4; ++i)
                #pragma unroll
                for (int j = 0; j < 4; ++j)
                    acc[i][j] = __builtin_amdgcn_mfma_f32_16x16x32_bf16(
                        af[i], bfr[j], acc[i][j], 0, 0, 0);
        }
        __syncthreads();
    }

    const int sec   = colBase / secN;
    const int cbase = colBase - sec * secN;
    unsigned short*       Cs = (sec == 0) ? P.C0 : ((sec == 1) ? P.C1 : P.C2);
    const unsigned short* ad = (sec == 0) ? P.a0 : ((sec == 1) ? P.a1 : P.a2);
    const int*            gx = (sec == 0) ? P.x0 : ((sec == 1) ? P.x1 : P.x2);
    const float*          bs = (sec == 0) ? P.b0 : ((sec == 1) ? P.b1 : P.b2);

    #pragma unroll
    for (int i = 0; i < 4; ++i) {
        #pragma unroll
        for (int r = 0; r < 4; ++r) {
            const int row = rowBase + wm + i * 16 + quad * 4 + r;
            if (row >= M) continue;
            const int arow = gx ? gx[row] : row;
            const unsigned short* addr = ad ? ad + (size_t)arow * secN : nullptr;
            unsigned short* crow = Cs + (size_t)row * secN;
            #pragma unroll
            for (int j = 0; j < 4; ++j) {
                const int col = cbase + wn + j * 16 + l16;
                float v = acc[i][j][r];
                if (bs) v += bs[col];
                if (addr) v += b2f(addr[col]);
                if (relu) v = fmaxf(v, 0.0f);
                crow[col] = f2b(v);
            }
        }
    }
}

// ---------------------------------------------------------------------------
// W[K][N] fp32 -> Wt[N][K] bf16
// ---------------------------------------------------------------------------
__global__ __launch_bounds__(256) void transpose_cast_kernel(
    const float* __restrict__ W, unsigned short* __restrict__ Wt, int K, int N)
{
    __shared__ float t[32][33];
    const int n0 = blockIdx.x << 5, k0 = blockIdx.y << 5;
    const int tx = threadIdx.x & 31, ty = threadIdx.x >> 5;
    #pragma unroll
    for (int r = 0; r < 32; r += 8)
        t[ty + r][tx] = W[(size_t)(k0 + ty + r) * N + n0 + tx];
    __syncthreads();
    #pragma unroll
    for (int r = 0; r < 32; r += 8)
        Wt[(size_t)(n0 + ty + r) * K + k0 + tx] = f2b(t[tx][ty + r]);
}

// ---------------------------------------------------------------------------
// LayerNorm in place over bf16 rows of width 512. One wave per row.
// ---------------------------------------------------------------------------
__global__ __launch_bounds__(256) void ln_kernel(
    unsigned short* __restrict__ x, const float* __restrict__ g,
    const float* __restrict__ b, int M)
{
    const int row = blockIdx.x * 4 + (threadIdx.x >> 6);
    if (row >= M) return;
    const int lane = threadIdx.x & 63;
    unsigned short* xr = x + (size_t)row * DMODEL;

    float vals[8];
    float s = 0.f, s2 = 0.f;
    #pragma unroll
    for (int i = 0; i < 8; ++i) {
        const float v = b2f(xr[lane + i * 64]);
        vals[i] = v; s += v; s2 += v * v;
    }
    #pragma unroll
    for (int o = 32; o > 0; o >>= 1) {
        s  += __shfl_down(s, o);
        s2 += __shfl_down(s2, o);
    }
    s  = __shfl(s, 0);
    s2 = __shfl(s2, 0);
    const float m = s * (1.0f / DMODEL);
    const float var = s2 * (1.0f / DMODEL) - m * m;
    const float r = rsqrtf(var + 1e-5f);
    #pragma unroll
    for (int i = 0; i < 8; ++i) {
        const int c = lane + i * 64;
        xr[c] = f2b((vals[i] - m) * r * g[c] + b[c]);
    }
}

// ---------------------------------------------------------------------------
// CSR build: histogram -> single-block scan -> scatter
// ---------------------------------------------------------------------------
__global__ __launch_bounds__(256) void hist_kernel(
    const int* __restrict__ dst, int* __restrict__ cnt, int ne)
{
    const int j = blockIdx.x * 256 + threadIdx.x;
    if (j < ne) atomicAdd(&cnt[dst[j]], 1);
}

__global__ __launch_bounds__(1024) void scan_kernel(
    const int* __restrict__ cnt, int* __restrict__ off,
    int* __restrict__ cur, int n)
{
    __shared__ int part[1024];
    const int t = threadIdx.x;
    const int chunk = (n + 1023) >> 10;
    const int lo = t * chunk;
    int hi = lo + chunk; if (hi > n) hi = n;
    int s = 0;
    for (int i = lo; i < hi; ++i) s += cnt[i];
    part[t] = s;
    __syncthreads();
    #pragma unroll
    for (int o = 1; o < 1024; o <<= 1) {
        int v = (t >= o) ? part[t - o] : 0;
        __syncthreads();
        part[t] += v;
        __syncthreads();
    }
    int base = (t == 0) ? 0 : part[t - 1];
    const int total = part[1023];
    for (int i = lo; i < hi; ++i) {
        const int c = cnt[i];
        off[i] = base; cur[i] = base;
        base += c;
    }
    if (t == 1023) off[n] = total;
}

__global__ __launch_bounds__(256) void scatter_kernel(
    const int* __restrict__ dst, int* __restrict__ cur,
    int* __restrict__ idx, int ne)
{
    const int j = blockIdx.x * 256 + threadIdx.x;
    if (j < ne) {
        const int p = atomicAdd(&cur[dst[j]], 1);
        idx[p] = j;
    }
}

// ---------------------------------------------------------------------------
// Fused CSR attention, wave-parallel over incident edges.
// ---------------------------------------------------------------------------
__global__ __launch_bounds__(256) void attend_kernel(
    unsigned short* __restrict__ q,
    const unsigned short* __restrict__ k,
    const unsigned short* __restrict__ v,
    const unsigned short* __restrict__ efeat,
    const int* __restrict__ src,
    const int* __restrict__ off, const int* __restrict__ idx,
    int nseg)
{
    __shared__ float accS[4][DMODEL];   // 8 KB
    __shared__ float zS[4][NH];

    const int seg = blockIdx.x;
    if (seg >= nseg) return;
    const int t = threadIdx.x;
    const int wave = t >> 6, lane = t & 63;
    const int c8 = lane * 8;
    unsigned short* qrow = q + (size_t)seg * DMODEL;

    const us8v q8 = *(const us8v*)(qrow + c8);
    float qv[8];
    #pragma unroll
    for (int j = 0; j < 8; ++j) qv[j] = b2f(q8[j]);

    float acc[8] = {0.f, 0.f, 0.f, 0.f, 0.f, 0.f, 0.f, 0.f};
    float zsum = 0.f;
    const int lo = off[seg], hi = off[seg + 1];
    for (int jj = lo + wave; jj < hi; jj += 4) {
        const int e = idx[jj];
        const int s = src[e];
        const us8v k8 = *(const us8v*)(k + (size_t)s * DMODEL + c8);
        const us8v v8 = *(const us8v*)(v + (size_t)s * DMODEL + c8);
        float p = 0.f;
        float vv[8];
        if (efeat) {
            const us8v e8 = *(const us8v*)(efeat + (size_t)e * DMODEL + c8);
            #pragma unroll
            for (int j = 0; j < 8; ++j) {
                const float ef = b2f(e8[j]);
                p = fmaf(b2f(k8[j]) + ef, qv[j], p);
                vv[j] = b2f(v8[j]) + ef;
            }
        } else {
            #pragma unroll
            for (int j = 0; j < 8; ++j) {
                p = fmaf(b2f(k8[j]), qv[j], p);
                vv[j] = b2f(v8[j]);
            }
        }
        p += __shfl_xor(p, 1);
        p += __shfl_xor(p, 2);
        p += __shfl_xor(p, 4);
        float sc = p * 0.125f;                    // 1/sqrt(64)
        sc = fminf(fmaxf(sc, -10.0f), 10.0f);
        sc = __expf(sc);
        zsum += sc;
        #pragma unroll
        for (int j = 0; j < 8; ++j) acc[j] = fmaf(sc, vv[j], acc[j]);
    }

    #pragma unroll
    for (int j = 0; j < 8; ++j) accS[wave][c8 + j] = acc[j];
    if ((lane & 7) == 0) zS[wave][lane >> 3] = zsum;
    __syncthreads();

    const int c0 = t * 2;
    const int h = c0 >> 6;
    const float a0 = accS[0][c0] + accS[1][c0] + accS[2][c0] + accS[3][c0];
    const float a1 = accS[0][c0 + 1] + accS[1][c0 + 1] + accS[2][c0 + 1] + accS[3][c0 + 1];
    const float z  = zS[0][h] + zS[1][h] + zS[2][h] + zS[3][h];
    const float rz = 1.0f / z;
    ushort2 o2;
    o2.x = f2b(a0 * rz);
    o2.y = f2b(a1 * rz);
    *(ushort2*)(qrow + c0) = o2;
}

// ---------------------------------------------------------------------------
__global__ __launch_bounds__(256) void gather_rel_kernel(
    const float* __restrict__ rel, const int* __restrict__ ef,
    unsigned short* __restrict__ lg)
{
    const int idx = blockIdx.x * 256 + threadIdx.x;
    if (idx >= NEDGES * DMODEL) return;
    const int e = idx >> 9;
    const int col = idx & 511;
    lg[idx] = f2b(rel[(size_t)ef[e] * DMODEL + col]);
}

__global__ __launch_bounds__(256) void cast_f2b_kernel(
    const float* __restrict__ in, unsigned short* __restrict__ out, int n)
{
    const int idx = blockIdx.x * 256 + threadIdx.x;
    if (idx < n) out[idx] = f2b(in[idx]);
}

__global__ __launch_bounds__(256) void cast_b2f_kernel(
    const unsigned short* __restrict__ in, float* __restrict__ out, int n)
{
    const int idx = blockIdx.x * 256 + threadIdx.x;
    if (idx < n) out[idx] = b2f(in[idx]);
}

__global__ __launch_bounds__(256) void zero_kernel(float4* __restrict__ p, int n4)
{
    const int idx = blockIdx.x * 256 + threadIdx.x;
    if (idx < n4) p[idx] = make_float4(0.f, 0.f, 0.f, 0.f);
}

// ---------------------------------------------------------------------------
static inline dim3 gemm_grid(int M, int N)
{
    return dim3(N / BN, (M + BM - 1) / BM);   // N-tiles FAST
}

static inline void mgemm(hipStream_t st, const unsigned short* A, const unsigned short* Bt,
                         const float* bias, const unsigned short* add, const int* gidx,
                         unsigned short* C, int M, int K, int N, int relu)
{
    GemmDst P = {C, nullptr, nullptr, add, nullptr, nullptr,
                 gidx, nullptr, nullptr, bias, nullptr, nullptr};
    mfma_gemm_kernel<<<gemm_grid(M, N), 256, 0, st>>>(A, Bt, P, M, K, N, N, relu);
}

static inline void mgemm_qkv(hipStream_t st, const unsigned short* A, const unsigned short* Bt,
                             const float* biasQ,
                             const unsigned short* addQ, const int* gxQ,
                             const unsigned short* addKV, const int* gxKV,
                             unsigned short* Cq, unsigned short* Ck, unsigned short* Cv,
                             int M, int K)
{
    GemmDst P = {Cq, Ck, Cv, addQ, addKV, addKV,
                 gxQ, gxKV, gxKV, biasQ, nullptr, nullptr};
    mfma_gemm_kernel<<<gemm_grid(M, 1536), 256, 0, st>>>(A, Bt, P, M, K, 1536, 512, 0);
}

static inline void tcast(hipStream_t st, const float* W, unsigned short* Wt, int K, int N)
{
    dim3 g(N / 32, K / 32);
    transpose_cast_kernel<<<g, 256, 0, st>>>(W, Wt, K, N);
}
static inline void zero(hipStream_t st, void* p, size_t nfloats)
{
    const int n4 = (int)(nfloats / 4);
    zero_kernel<<<(n4 + 255) / 256, 256, 0, st>>>((float4*)p, n4);
}

extern "C" void kernel_launch(void* const* d_in, const int* in_sizes, int n_in,
                              void* d_out, int out_size, void* d_ws, size_t ws_size,
                              hipStream_t stream)
{
    const float* x_in      = (const float*)d_in[0];
    const int*   edge_feat = (const int*)d_in[1];
    const int*   src_ids   = (const int*)d_in[2];
    const int*   dst_ids   = (const int*)d_in[3];
    const int*   lg_src    = (const int*)d_in[4];
    const int*   lg_dst    = (const int*)d_in[5];
    const float* rel_embed = (const float*)d_in[6];

    const float* n_Wq = (const float*)d_in[7];   const float* n_bq = (const float*)d_in[8];
    const float* n_Wk = (const float*)d_in[9];   const float* n_Wv = (const float*)d_in[10];
    const float* n_Wo = (const float*)d_in[11];  const float* n_bo = (const float*)d_in[12];
    const float* n_lg = (const float*)d_in[13];  const float* n_lb = (const float*)d_in[14];
    const float* n_f1 = (const float*)d_in[15];  const float* n_fb1 = (const float*)d_in[16];
    const float* n_f2 = (const float*)d_in[17];  const float* n_fb2 = (const float*)d_in[18];
    const float* n_fg = (const float*)d_in[19];  const float* n_fb = (const float*)d_in[20];

    const float* e_Wq = (const float*)d_in[21];  const float* e_bq = (const float*)d_in[22];
    const float* e_Wk = (const float*)d_in[23];  const float* e_Wv = (const float*)d_in[24];
    const float* e_Wo = (const float*)d_in[25];  const float* e_bo = (const float*)d_in[26];
    const float* e_lg = (const float*)d_in[27];  const float* e_lb = (const float*)d_in[28];
    const float* e_f1 = (const float*)d_in[29];  const float* e_fb1 = (const float*)d_in[30];
    const float* e_f2 = (const float*)d_in[31];  const float* e_fb2 = (const float*)d_in[32];
    const float* e_fg = (const float*)d_in[33];  const float* e_fb = (const float*)d_in[34];

    const int XSZ  = NNODES * DMODEL;
    const int LGSZ = NEDGES * DMODEL;

    // ---- workspace layout ---------------------------------------------------
    char* ws = (char*)d_ws;
    unsigned short* lg16  = (unsigned short*)(ws);               // 51,200,000 B
    unsigned short* ve16  = (unsigned short*)(ws + 51200000);    // 51,200,000 B
    int* n_off = (int*)(ws + 102400000);
    int* n_cur = (int*)(ws + 102420480);
    int* n_idx = (int*)(ws + 102440960);
    int* e_off = (int*)(ws + 102641664);
    int* e_cur = (int*)(ws + 102842368);
    int* e_idx = (int*)(ws + 103043072);                         // ends 103.84 MB
    unsigned short* xbufA = (unsigned short*)(ws + 110400000);   // 5,120,000 B
    unsigned short* xbufB = (unsigned short*)(ws + 115520000);   // 5,120,000 B

    // ---- d_out scratch (112.64 MB) -----------------------------------------
    char* ob = (char*)d_out;
    unsigned short* qe16 = (unsigned short*)(ob);                // 51.2 MB
    unsigned short* ke16 = (unsigned short*)(ob + 51200000);     // 51.2 MB
    unsigned short* nq16 = (unsigned short*)(ob);
    unsigned short* nk16 = (unsigned short*)(ob + 5120000);
    unsigned short* nv16 = (unsigned short*)(ob + 10240000);
    unsigned short* nhid = (unsigned short*)(ob);                // 20.48 MB (node FFN hidden)
    unsigned short* hid25 = (unsigned short*)(ob);               // 102.4 MB (edge FFN hidden)
    unsigned short* wtq  = (unsigned short*)(ob + 102400000);    // q|k|v contiguous
    unsigned short* wtk  = (unsigned short*)(ob + 102924288);
    unsigned short* wtv  = (unsigned short*)(ob + 103448576);
    unsigned short* wto  = (unsigned short*)(ob + 103972864);
    unsigned short* wtf1 = (unsigned short*)(ob + 104497152);    // 2 MB
    unsigned short* wtf2 = (unsigned short*)(ob + 106594304);    // 2 MB (ends 108.7 MB)

    // ---- init + CSR build ---------------------------------------------------
    cast_f2b_kernel<<<(XSZ + 255) / 256, 256, 0, stream>>>(x_in, xbufA, XSZ);
    gather_rel_kernel<<<(LGSZ + 255) / 256, 256, 0, stream>>>(rel_embed, edge_feat, lg16);

    zero(stream, n_cur, NNODES);
    zero(stream, e_cur, NEDGES);
    hist_kernel<<<(NEDGES + 255) / 256, 256, 0, stream>>>(dst_ids, n_cur, NEDGES);
    hist_kernel<<<(NELG + 255) / 256, 256, 0, stream>>>(lg_dst, e_cur, NELG);
    scan_kernel<<<1, 1024, 0, stream>>>(n_cur, n_off, n_cur, NNODES);
    scan_kernel<<<1, 1024, 0, stream>>>(e_cur, e_off, e_cur, NEDGES);
    scatter_kernel<<<(NEDGES + 255) / 256, 256, 0, stream>>>(dst_ids, n_cur, n_idx, NEDGES);
    scatter_kernel<<<(NELG + 255) / 256, 256, 0, stream>>>(lg_dst, e_cur, e_idx, NELG);

    unsigned short* xc = xbufA;
    unsigned short* xn = xbufB;

    for (int i = 0; i < NLAYERS; ++i) {
        const size_t wo  = (size_t)i * DMODEL * DMODEL;
        const size_t bo_ = (size_t)i * DMODEL;
        const size_t f1o = (size_t)i * DMODEL * 4 * DMODEL;
        const size_t b1o = (size_t)i * 4 * DMODEL;
        const size_t f2o = (size_t)i * 4 * DMODEL * DMODEL;

        // ================= node update (reads xc, lg16) =================
        tcast(stream, n_Wq + wo, wtq, 512, 512);
        tcast(stream, n_Wk + wo, wtk, 512, 512);
        tcast(stream, n_Wv + wo, wtv, 512, 512);
        tcast(stream, n_Wo + wo, wto, 512, 512);
        tcast(stream, n_f1 + f1o, wtf1, 512, 2048);
        tcast(stream, n_f2 + f2o, wtf2, 2048, 512);

        mgemm_qkv(stream, xc, wtq, n_bq + bo_,
                  nullptr, nullptr, nullptr, nullptr,
                  nq16, nk16, nv16, NNODES, 512);

        attend_kernel<<<NNODES, 256, 0, stream>>>(
            nq16, nk16, nv16, lg16, src_ids, n_off, n_idx, NNODES);

        mgemm(stream, nq16, wto, n_bo + bo_, xc, nullptr, xn, NNODES, 512, 512, 0);
        ln_kernel<<<(NNODES + 3) / 4, 256, 0, stream>>>(xn, n_lg + bo_, n_lb + bo_, NNODES);
        mgemm(stream, xn, wtf1, n_fb1 + b1o, nullptr, nullptr, nhid, NNODES, 512, 2048, 1);
        mgemm(stream, nhid, wtf2, n_fb2 + bo_, xn, nullptr, xn, NNODES, 2048, 512, 0);
        ln_kernel<<<(NNODES + 3) / 4, 256, 0, stream>>>(xn, n_fg + bo_, n_fb + bo_, NNODES);

        // ================= edge update (reads PRE-update xc) =================
        tcast(stream, e_Wq + wo, wtq, 512, 512);
        tcast(stream, e_Wk + wo, wtk, 512, 512);
        tcast(stream, e_Wv + wo, wtv, 512, 512);
        tcast(stream, e_Wo + wo, wto, 512, 512);

        mgemm_qkv(stream, lg16, wtq, e_bq + bo_,
                  xc, dst_ids, xc, src_ids,
                  qe16, ke16, ve16, NEDGES, 512);

        attend_kernel<<<NEDGES, 256, 0, stream>>>(
            qe16, ke16, ve16, nullptr, lg_src, e_off, e_idx, NEDGES);

        mgemm(stream, qe16, wto, e_bo + bo_, lg16, nullptr, lg16, NEDGES, 512, 512, 0);
        ln_kernel<<<(NEDGES + 3) / 4, 256, 0, stream>>>(lg16, e_lg + bo_, e_lb + bo_, NEDGES);

        tcast(stream, e_f1 + f1o, wtf1, 512, 2048);
        tcast(stream, e_f2 + f2o, wtf2, 2048, 512);
        // FFN over edges, 2 chunks of 25000 rows; hidden uses full dead d_out
        for (int c = 0; c < 2; ++c) {
            unsigned short* y1c = lg16 + (size_t)c * 25000 * DMODEL;
            mgemm(stream, y1c, wtf1, e_fb1 + b1o, nullptr, nullptr, hid25, 25000, 512, 2048, 1);
            mgemm(stream, hid25, wtf2, e_fb2 + bo_, y1c, nullptr, y1c, 25000, 2048, 512, 0);
        }
        ln_kernel<<<(NEDGES + 3) / 4, 256, 0, stream>>>(lg16, e_fg + bo_, e_fb + bo_, NEDGES);

        unsigned short* t = xc; xc = xn; xn = t;
    }

    // final: bf16 -> fp32 d_out (all d_out scratch dead now)
    float* out_f = (float*)d_out;
    cast_b2f_kernel<<<(XSZ + 255) / 256, 256, 0, stream>>>(xc, out_f, XSZ);
    cast_b2f_kernel<<<(LGSZ + 255) / 256, 256, 0, stream>>>(lg16, out_f + XSZ, LGSZ);
}